// Round 11
// baseline (160.420 us; speedup 1.0000x reference)
//
#include <hip/hip_runtime.h>
#include <hip/hip_fp16.h>
#include <math.h>

// ---------------------------------------------------------------------------
// GCN 2-layer, bucket-partitioned CSR build + wide-parallel fp16 gathers.
// R25: widen gather memory parallelism. Evidence: g1+g2 ~ 90us (56% of
// total) with FETCH only 23.5MB (R21 probe) -- L2-latency/concurrency-bound,
// ~6x off the ~14us request-rate floor. R24 confirmed the sort side is at
// its floor (~40us, 5 designs bracketed). Change ONLY the gathers:
//   g1: 8 lanes/node = (slot 0..3) x (feature-half 0/1). Each lane loads ONE
//       uint4 per edge (vs two) -> acc[8] (vs 16), ~25 fewer VGPRs, chains
//       halved, same request count issued from 2x more waves. Reduce:
//       shfl_xor 2,4 (slots), epilogue per half, shfl_xor 1 (halves).
//   g2: 8 lanes/node, ~2 edges/lane, xor 1,2,4 reduce.
//   Both lb(256,8) -> 32 waves/CU (was 24).
// k1b/k2 byte-identical to R24 (split-hist, proven passing, 160.4us).
// Pipeline: memset(cursors) -> k1b_fat(scatter||gemm) -> k2 -> g1 -> g2.
// ---------------------------------------------------------------------------

#define BSH 9
#define BNODES 512
#define P1 512
#define GROWS 64
#define K2BUF 10240
#define BCAP 12288
#define EPT 16
#define EPT2 12
#define CSTR 16

struct alignas(8) Half4 { __half x, y, z, w; };

// ---- k1b FAT: [reg-cached split-hist LDS-sorted scatter] || [gemm1] ----
__global__ void k1b_fat(const int* __restrict__ src, const int* __restrict__ dst,
                        int* __restrict__ cursor,
                        unsigned int* __restrict__ staging,
                        const float* __restrict__ x, const float* __restrict__ W1,
                        Half4* __restrict__ g1h, int NBK, int n, int E) {
    __shared__ int smem[7940];          // 31760 B (scatter); gemm uses 8KB
    int b = blockIdx.x;
    int t = threadIdx.x;
    if (b < P1) {
        int (*hist)[256] = (int(*)[256])smem;   // [4][256] per-wave counts
        int* cs    = smem + 1024;       // [256] exclusive bucket prefix
        int* rbase = smem + 1280;       // [256]
        int* wsum  = smem + 1536;       // [4]
        int* buf   = smem + 1540;       // [3200]
        int* gaddr = smem + 4740;       // [3200]
        int w = t >> 6;                 // wave id 0..3
        #pragma unroll
        for (int g = 0; g < 4; ++g) hist[g][t] = 0;
        __syncthreads();
        int slice = (E + P1 - 1) / P1;
        int e0 = b * slice, e1 = min(E, e0 + slice);
        int len = e1 - e0;
        // single global read into registers
        int dl[EPT], sl[EPT];
        int cnt = 0;
        for (int e = e0 + t; e < e1 && cnt < EPT; e += 256, ++cnt) {
            dl[cnt] = dst[e];
            sl[cnt] = src[e];
        }
        // per-wave count: collisions only within own wave
        for (int i = 0; i < cnt; ++i)
            atomicAdd(&hist[w][dl[i] >> BSH], 1);
        __syncthreads();
        // thread k: total h + per-wave prefixes written back IN PLACE
        int h0 = hist[0][t], h1 = hist[1][t], h2 = hist[2][t], h3 = hist[3][t];
        int h = h0 + h1 + h2 + h3;
        hist[0][t] = 0;
        hist[1][t] = h0;
        hist[2][t] = h0 + h1;
        hist[3][t] = h0 + h1 + h2;
        // wave-shfl inclusive scan over 256 totals (4 waves), then combine
        int xx = h;
        #pragma unroll
        for (int o = 1; o < 64; o <<= 1) {
            int v = __shfl_up(xx, o);
            if ((t & 63) >= o) xx += v;
        }
        if ((t & 63) == 63) wsum[t >> 6] = xx;
        __syncthreads();
        #pragma unroll
        for (int i = 0; i < 4; ++i)
            if (i < w) xx += wsum[i];
        cs[t] = xx - h;  // exclusive
        rbase[t] = (h > 0 && t < NBK) ? atomicAdd(&cursor[t * CSTR], h) : 0;
        __syncthreads();
        // place: atomicAdd on own wave's prefix cell RETURNS in-bucket ordinal
        for (int i = 0; i < cnt; ++i) {
            int d = dl[i], s = sl[i];
            int k = d >> BSH;
            int ord = atomicAdd(&hist[w][k], 1);   // = wave-prefix + tk
            int pos = cs[k] + ord;
            buf[pos] = (s << BSH) | (d & (BNODES - 1));
            int g = rbase[k] + ord;
            gaddr[pos] = (g < BCAP) ? (k * BCAP + g) : -1;  // overflow guard
        }
        __syncthreads();
        // coalesced copy-out
        for (int p = t; p < len; p += 256) {
            int a = gaddr[p];
            if (a >= 0) staging[a] = (unsigned int)buf[p];
        }
    } else {
        // ---- gemm: partial-K per lane, shfl-halving reduce, no x staging ----
        float4* sW4 = (float4*)smem;    // [512] = W1 [128][16] as [k][c4]
        for (int i = t; i < 512; i += 256) sW4[i] = ((const float4*)W1)[i];
        __syncthreads();
        int r = t >> 2, c4 = t & 3;
        int row = (b - P1) * GROWS + r;
        if (row >= n) return;           // all 4 lanes of a row exit together
        float acc[16];
        #pragma unroll
        for (int j = 0; j < 16; ++j) acc[j] = 0.f;
        const float4* xr = (const float4*)(x + (size_t)row * 128);
        #pragma unroll
        for (int q = 0; q < 8; ++q) {
            float4 xv = xr[q * 4 + c4];       // cols 16q+4c4 .. +3 (64B segs/wave)
            #pragma unroll
            for (int j = 0; j < 4; ++j) {
                int k = q * 16 + c4 * 4 + j;
                float s = (j == 0) ? xv.x : (j == 1) ? xv.y : (j == 2) ? xv.z : xv.w;
                #pragma unroll
                for (int cq = 0; cq < 4; ++cq) {
                    float4 w2 = sW4[k * 4 + cq];
                    acc[cq * 4 + 0] += s * w2.x; acc[cq * 4 + 1] += s * w2.y;
                    acc[cq * 4 + 2] += s * w2.z; acc[cq * 4 + 3] += s * w2.w;
                }
            }
        }
        // 2-step tree-halving reduce across the 4 row-lanes
        #pragma unroll
        for (int j = 0; j < 8; ++j) {
            float send = (c4 & 1) ? acc[j] : acc[j + 8];
            float recv = __shfl_xor(send, 1);
            acc[j] = ((c4 & 1) ? acc[j + 8] : acc[j]) + recv;
        }
        #pragma unroll
        for (int j = 0; j < 4; ++j) {
            float send = (c4 & 2) ? acc[j] : acc[j + 4];
            float recv = __shfl_xor(send, 2);
            acc[j] = ((c4 & 2) ? acc[j + 4] : acc[j]) + recv;
        }
        // lane c4 holds features base..base+3, base = 8*(c4&1) + 4*((c4&2)>>1)
        int cidx = 2 * (c4 & 1) + ((c4 & 2) >> 1);
        Half4 hh;
        hh.x = __float2half(acc[0]); hh.y = __float2half(acc[1]);
        hh.z = __float2half(acc[2]); hh.w = __float2half(acc[3]);
        g1h[(size_t)row * 4 + cidx] = hh;   // unscaled; k2 applies dinv
    }
}

// ---- k2: per-bucket CSR (split-hist in-place counters) + meta ----
__global__ void __launch_bounds__(1024) k2_bucket(
        const unsigned int* __restrict__ staging, const int* __restrict__ cursor,
        int* __restrict__ csr, int* __restrict__ deg, float* __restrict__ dinv,
        int* __restrict__ row_start, Half4* __restrict__ g1h, int n) {
    __shared__ int lh[8][BNODES];       // per-128-thread-group counts (16 KB)
    __shared__ int sc[BNODES], wsum[8];
    __shared__ float ldv[BNODES];
    __shared__ int buf[K2BUF];
    int kb = blockIdx.x, t = threadIdx.x;
    int wg = t >> 7;                    // group id 0..7 (2 waves each)
    int node0 = kb << BSH;
    int nloc = min(BNODES, n - node0);
    int ebase = kb * BCAP;
    int ecnt = min(cursor[kb * CSTR], BCAP);
    // flat-stride zero of ALL 8x512 counters
    for (int j = t; j < 8 * BNODES; j += 1024) ((int*)lh)[j] = 0;
    __syncthreads();
    // single global read into registers
    int el[EPT2];
    int cnt = 0;
    for (int e = t; e < ecnt && cnt < EPT2; e += 1024, ++cnt)
        el[cnt] = (int)staging[ebase + e];
    for (int i = 0; i < cnt; ++i)
        atomicAdd(&lh[wg][el[i] & (BNODES - 1)], 1);
    __syncthreads();
    // thread t<512: per-node total + group prefixes written back in place
    int own = 0;
    if (t < BNODES) {
        int pg = 0;
        #pragma unroll
        for (int g = 0; g < 8; ++g) {
            int c = lh[g][t];
            lh[g][t] = pg;
            pg += c;
        }
        own = pg;
    }
    // wave-shfl inclusive scan over 512 totals (waves 0..7)
    int xx = own;
    #pragma unroll
    for (int o = 1; o < 64; o <<= 1) {
        int v = __shfl_up(xx, o);
        if ((t & 63) >= o) xx += v;
    }
    if (t < BNODES && (t & 63) == 63) wsum[t >> 6] = xx;
    __syncthreads();
    if (t < BNODES) {
        int wv = t >> 6;
        #pragma unroll
        for (int i = 0; i < 8; ++i)
            if (i < wv) xx += wsum[i];
        int excl = xx - own;
        if (t < nloc) {
            deg[node0 + t] = own;
            row_start[node0 + t] = ebase + excl;
            float dv = rsqrtf((float)(own + 1));  // +1 self-loop
            dinv[node0 + t] = dv;
            ldv[t] = dv;
        }
        sc[t] = excl;
    }
    __syncthreads();
    if (ecnt <= K2BUF) {
        for (int i = 0; i < cnt; ++i) {
            int p = el[i];
            int loc = p & (BNODES - 1);
            int ord = atomicAdd(&lh[wg][loc], 1);   // = group-prefix + tk
            buf[sc[loc] + ord] = p >> BSH;
        }
        __syncthreads();
        for (int p = t; p < ecnt; p += 1024)
            csr[ebase + p] = buf[p];
    } else {  // statistically unreachable fallback
        for (int i = 0; i < cnt; ++i) {
            int p = el[i];
            int loc = p & (BNODES - 1);
            int ord = atomicAdd(&lh[wg][loc], 1);
            csr[ebase + sc[loc] + ord] = p >> BSH;
        }
    }
    for (int j = t; j < nloc * 4; j += 1024) {
        float dv = ldv[j >> 2];
        Half4 v = g1h[(size_t)node0 * 4 + j];
        v.x = __float2half(__half2float(v.x) * dv);
        v.y = __float2half(__half2float(v.y) * dv);
        v.z = __float2half(__half2float(v.z) * dv);
        v.w = __float2half(__half2float(v.w) * dv);
        g1h[(size_t)node0 * 4 + j] = v;
    }
}

// ---- gather1: 8 lanes/node = (slot 0..3) x (half 0/1); ONE uint4/lane/edge;
//      acc[8]; reduce xor 2,4 (slots) -> epilogue per half -> xor 1 ----
__global__ void __launch_bounds__(256, 8) k_gather1(
        const uint4* __restrict__ g1q, const int* __restrict__ csr,
        const int* __restrict__ row_start, const int* __restrict__ deg,
        const float* __restrict__ dinv, const float* __restrict__ b1,
        const float* __restrict__ W2, Half4* __restrict__ g2h, int n) {
    int idx = blockIdx.x * 256 + threadIdx.x;
    int i = idx >> 3, l = idx & 7;
    if (i >= n) return;
    int half = l & 1;      // feature half: 0 -> g1q[2s], 1 -> g1q[2s+1]
    int slot = l >> 1;     // edge slot 0..3
    int off = row_start[i], dg = deg[i];
    float acc[8];
    #pragma unroll
    for (int j = 0; j < 8; ++j) acc[j] = 0.f;
    if (slot == 0) {   // self-loop: lanes 0(h0), 1(h1) load own half
        uint4 p = g1q[2 * (size_t)i + half];
        const __half2* hp = reinterpret_cast<const __half2*>(&p);
        #pragma unroll
        for (int j = 0; j < 4; ++j) {
            float2 f = __half22float2(hp[j]);
            acc[2 * j] += f.x; acc[2 * j + 1] += f.y;
        }
    }
    // ~4 edges/lane; ONE 16B load each; unroll 4 => 4 csr + 4 msg in flight
    #pragma unroll 4
    for (int k = slot; k < dg; k += 4) {
        int s = csr[off + k];
        uint4 p = g1q[2 * (size_t)s + half];
        const __half2* hp = reinterpret_cast<const __half2*>(&p);
        #pragma unroll
        for (int j = 0; j < 4; ++j) {
            float2 f = __half22float2(hp[j]);
            acc[2 * j] += f.x; acc[2 * j + 1] += f.y;
        }
    }
    // reduce across the 4 slots (same half): xor 2 then xor 4
    #pragma unroll
    for (int j = 0; j < 8; ++j) acc[j] += __shfl_xor(acc[j], 2);
    #pragma unroll
    for (int j = 0; j < 8; ++j) acc[j] += __shfl_xor(acc[j], 4);
    // epilogue: each lane handles its half's 8 features
    float di = dinv[i];
    int fb = half * 8;
    float o0 = 0.f, o1 = 0.f, o2 = 0.f;
    #pragma unroll
    for (int j = 0; j < 8; ++j) {
        int f = fb + j;
        float z = fmaxf(0.f, di * acc[j] + b1[f]);
        o0 += z * W2[f * 3 + 0];
        o1 += z * W2[f * 3 + 1];
        o2 += z * W2[f * 3 + 2];
    }
    // combine the two halves
    o0 += __shfl_xor(o0, 1); o1 += __shfl_xor(o1, 1); o2 += __shfl_xor(o2, 1);
    if (l != 0) return;
    Half4 g;
    g.x = __float2half(di * o0); g.y = __float2half(di * o1);
    g.z = __float2half(di * o2); g.w = __float2half(0.f);
    g2h[i] = g;
}

// ---- gather2: 8 lanes/node, ~2 edges/lane, xor 1,2,4 reduce ----
__global__ void __launch_bounds__(256, 8) k_gather2(
        const Half4* __restrict__ g2h, const int* __restrict__ csr,
        const int* __restrict__ row_start, const int* __restrict__ deg,
        const float* __restrict__ dinv, const float* __restrict__ b2,
        float* __restrict__ out, int n) {
    int idx = blockIdx.x * 256 + threadIdx.x;
    int i = idx >> 3, l = idx & 7;
    if (i >= n) return;
    int off = row_start[i], dg = deg[i];
    float v0 = 0.f, v1 = 0.f, v2 = 0.f;
    if (l == 0) {
        Half4 s = g2h[i];
        v0 = __half2float(s.x); v1 = __half2float(s.y); v2 = __half2float(s.z);
    }
    #pragma unroll 2
    for (int e = l; e < dg; e += 8) {
        int s = csr[off + e];
        Half4 g = g2h[s];
        v0 += __half2float(g.x); v1 += __half2float(g.y); v2 += __half2float(g.z);
    }
    v0 += __shfl_xor(v0, 1); v1 += __shfl_xor(v1, 1); v2 += __shfl_xor(v2, 1);
    v0 += __shfl_xor(v0, 2); v1 += __shfl_xor(v1, 2); v2 += __shfl_xor(v2, 2);
    v0 += __shfl_xor(v0, 4); v1 += __shfl_xor(v1, 4); v2 += __shfl_xor(v2, 4);
    if (l >= 3) return;
    float di = dinv[i];
    float a0 = di * v0 + b2[0];
    float a1 = di * v1 + b2[1];
    float a2 = di * v2 + b2[2];
    float m = fmaxf(a0, fmaxf(a1, a2));
    float lse = logf(expf(a0 - m) + expf(a1 - m) + expf(a2 - m));
    float r = (l == 0) ? a0 : (l == 1) ? a1 : a2;
    out[(size_t)i * 3 + l] = r - m - lse;
}

// ======================== launch ========================
extern "C" void kernel_launch(void* const* d_in, const int* in_sizes, int n_in,
                              void* d_out, int out_size, void* d_ws, size_t ws_size,
                              hipStream_t stream) {
    const float* x  = (const float*)d_in[0];
    const int*   ei = (const int*)d_in[1];      // [2][E]
    const float* W1 = (const float*)d_in[2];    // [128][16]
    const float* b1 = (const float*)d_in[3];    // [16]
    const float* W2 = (const float*)d_in[4];    // [16][3]
    const float* b2 = (const float*)d_in[5];    // [3]
    float* out = (float*)d_out;

    const int n = in_sizes[0] / 128;   // 100000
    const int E = in_sizes[1] / 2;     // 1600000
    const int* src = ei;
    const int* dst = ei + E;

    const int NBK = (n + BNODES - 1) >> BSH;   // 196

    auto align = [](size_t v) { return (v + 255) & ~(size_t)255; };
    char* ws = (char*)d_ws;
    size_t o = 0;
    int* cursor   = (int*)(ws + o); o = align(o + (size_t)NBK * CSTR * 4);
    int* deg      = (int*)(ws + o); o = align(o + (size_t)n * 4);
    float* dinv   = (float*)(ws + o); o = align(o + (size_t)n * 4);
    int* row_start= (int*)(ws + o); o = align(o + (size_t)n * 4);
    unsigned int* staging = (unsigned int*)(ws + o); o = align(o + (size_t)NBK * BCAP * 4);
    int* csr      = (int*)(ws + o); o = align(o + (size_t)NBK * BCAP * 4);
    Half4* g1h    = (Half4*)(ws + o); o = align(o + (size_t)n * 4 * 8);
    Half4* g2h    = (Half4*)(ws + o); o = align(o + (size_t)n * 8);

    const int B = 256;
    int gGemm = (n + GROWS - 1) / GROWS;   // 1563
    int gn8   = (8 * n + B - 1) / B;       // 3125

    hipMemsetAsync(cursor, 0, (size_t)NBK * CSTR * 4, stream);
    k1b_fat<<<P1 + gGemm, B, 0, stream>>>(src, dst, cursor, staging,
                                          x, W1, g1h, NBK, n, E);
    k2_bucket<<<NBK, 1024, 0, stream>>>(staging, cursor, csr, deg, dinv, row_start, g1h, n);
    k_gather1<<<gn8, B, 0, stream>>>((const uint4*)g1h, csr, row_start, deg, dinv, b1, W2,
                                     g2h, n);
    k_gather2<<<gn8, B, 0, stream>>>(g2h, csr, row_start, deg, dinv, b2, out, n);
}